// Round 2
// baseline (432.797 us; speedup 1.0000x reference)
//
#include <hip/hip_runtime.h>

#define SIG0 0.17f
#define SIG1 4.86f

__device__ __constant__ float c_f1[5] = {0.05f, 0.25f, 0.4f, 0.25f, 0.05f};
__device__ __constant__ float c_filt0[25] = {
  0.04f,0.04f,0.05f,0.04f,0.04f,
  0.04f,0.03f,0.04f,0.03f,0.04f,
  0.05f,0.04f,0.05f,0.04f,0.05f,
  0.04f,0.03f,0.04f,0.03f,0.04f,
  0.04f,0.04f,0.05f,0.04f,0.04f};

static __device__ __forceinline__ int iclamp(int v, int lo, int hi){
  return v < lo ? lo : (v > hi ? hi : v);
}

// out[0:n) = h^(1/2.6), out[n:2n) = l^(1/2.6)
__global__ void gamma_kernel(const float* __restrict__ h, const float* __restrict__ l,
                             float* __restrict__ out, int n){
  int i = blockIdx.x*blockDim.x + threadIdx.x;
  if (i >= 2*n) return;
  float v = (i < n) ? h[i] : l[i-n];
  out[i] = powf(v, 0.3846153846153846f);
}

// down: replicate-pad-2, 5x5 separable conv, stride 2.  in: [32,H,W] -> out: [32,Ho,Wo]
__global__ void down_kernel(const float* __restrict__ in, float* __restrict__ out,
                            int H, int W, int Ho, int Wo){
  int idx = blockIdx.x*blockDim.x + threadIdx.x;
  int total = 32*Ho*Wo;
  if (idx >= total) return;
  int x = idx % Wo;
  int t = idx / Wo;
  int y = t % Ho;
  int b = t / Ho;
  const float* ip = in + (size_t)b*H*W;
  float sum = 0.f;
  #pragma unroll
  for (int i=0;i<5;i++){
    int yy = iclamp(2*y+i-2, 0, H-1);
    const float* rp = ip + (size_t)yy*W;
    float r = 0.f;
    #pragma unroll
    for (int j=0;j<5;j++){
      int xx = iclamp(2*x+j-2, 0, W-1);
      r += c_f1[j]*rp[xx];
    }
    sum += c_f1[i]*r;
  }
  out[(size_t)b*Ho*Wo + (size_t)y*Wo + x] = sum;
}

// lap: gk[y,x] -= up(g_{k+1})[y,x]   (in-place; each thread touches only its own pixel)
// up 2-D tap weight = 4 * f[dy] * f[dx]; the 4x is folded into wy ONLY.
__global__ void lap_kernel(float* __restrict__ gk, const float* __restrict__ g1,
                           int H, int W){
  int idx = blockIdx.x*blockDim.x + threadIdx.x;
  int total = 32*H*W;
  if (idx >= total) return;
  int Hg = H>>1, Wg = W>>1;
  int x = idx % W;
  int t = idx / W;
  int y = t % H;
  int b = t / H;
  const float* gp = g1 + (size_t)b*Hg*Wg;
  int y2 = y>>1, x2 = x>>1;
  int ry[3]; float wy[3];
  if ((y&1)==0){
    ry[0]=iclamp(y2-1,0,Hg-1); ry[1]=y2; ry[2]=iclamp(y2+1,0,Hg-1);
    wy[0]=0.2f; wy[1]=1.6f; wy[2]=0.2f;       // 4 * {0.05, 0.4, 0.05}
  } else {
    ry[0]=y2; ry[1]=iclamp(y2+1,0,Hg-1); ry[2]=y2;
    wy[0]=1.0f; wy[1]=1.0f; wy[2]=0.0f;       // 4 * {0.25, 0.25}
  }
  int rx[3]; float wx[3];
  if ((x&1)==0){
    rx[0]=iclamp(x2-1,0,Wg-1); rx[1]=x2; rx[2]=iclamp(x2+1,0,Wg-1);
    wx[0]=0.05f; wx[1]=0.4f; wx[2]=0.05f;     // raw taps (4x already in wy)
  } else {
    rx[0]=x2; rx[1]=iclamp(x2+1,0,Wg-1); rx[2]=x2;
    wx[0]=0.25f; wx[1]=0.25f; wx[2]=0.0f;
  }
  float up = 0.f;
  #pragma unroll
  for (int i=0;i<3;i++){
    const float* rp = gp + (size_t)ry[i]*Wg;
    float r = wx[0]*rp[rx[0]] + wx[1]*rp[rx[1]] + wx[2]*rp[rx[2]];
    up += wy[i]*r;
  }
  gk[idx] -= up;
}

// normalize both images' level-k laplacian, squared diff, block-reduce, atomicAdd.
// grid: (ceil(HW/256), 16)   blockIdx.y = batch b; h at b, l at b+16.
__global__ void normdiff_kernel(const float* __restrict__ lap, float* __restrict__ accum,
                                int H, int W, int lev, int last){
  int b = blockIdx.y;
  int idx = blockIdx.x*blockDim.x + threadIdx.x;
  int HW = H*W;
  float v = 0.f;
  if (idx < HW){
    int y = idx / W, x = idx % W;
    const float* lh = lap + (size_t)b*HW;
    const float* ll = lap + (size_t)(b+16)*HW;
    float ch = lh[idx], cl = ll[idx];
    float denh, denl;
    if (last){
      denh = fabsf(ch) + SIG1;
      denl = fabsf(cl) + SIG1;
    } else {
      denh = SIG0; denl = SIG0;
      #pragma unroll
      for (int i=0;i<5;i++){
        int yy = iclamp(y+i-2,0,H-1);
        const float* rh = lh + (size_t)yy*W;
        const float* rl = ll + (size_t)yy*W;
        #pragma unroll
        for (int j=0;j<5;j++){
          int xx = iclamp(x+j-2,0,W-1);
          float w = c_filt0[i*5+j];
          denh += w*fabsf(rh[xx]);
          denl += w*fabsf(rl[xx]);
        }
      }
    }
    float d = ch/denh - cl/denl;
    v = d*d;
  }
  // block reduction (blockDim = 256 = 4 waves)
  #pragma unroll
  for (int off=32; off>0; off>>=1) v += __shfl_down(v, off);
  __shared__ float swave[4];
  int tid = threadIdx.x;
  if ((tid & 63) == 0) swave[tid>>6] = v;
  __syncthreads();
  if (tid == 0){
    float s = swave[0]+swave[1]+swave[2]+swave[3];
    atomicAdd(&accum[lev*16 + b], s);
  }
}

// accum[k*16+b] = sum over pixels of d^2 for batch b, level k
__global__ void finalize_kernel(const float* __restrict__ accum, float* __restrict__ out){
  __shared__ float s[16];
  int b = threadIdx.x;
  if (b < 16){
    float m = 0.f;
    #pragma unroll
    for (int k=0;k<7;k++){
      int hw = (512>>k)*(512>>k);
      float mean = accum[k*16+b] / (float)hw;
      m += powf(mean, 0.3f);           // EXP_F/EXP_S = 0.6/2.0
    }
    m *= (1.0f/7.0f);
    s[b] = powf(m, 1.6666666666666667f); // 1/EXP_F
  }
  __syncthreads();
  if (b == 0){
    float t = 0.f;
    #pragma unroll
    for (int i=0;i<16;i++) t += s[i];
    out[0] = t * (1.0f/16.0f);
  }
}

extern "C" void kernel_launch(void* const* d_in, const int* in_sizes, int n_in,
                              void* d_out, int out_size, void* d_ws, size_t ws_size,
                              hipStream_t stream){
  const float* h = (const float*)d_in[0];
  const float* l = (const float*)d_in[1];
  float* out = (float*)d_out;
  float* ws = (float*)d_ws;

  int Hs[7], Ws_[7];
  size_t off[7];
  size_t cur = 0;
  for (int k=0;k<7;k++){
    Hs[k] = 512 >> k; Ws_[k] = 512 >> k;
    off[k] = cur;
    cur += (size_t)32 * Hs[k] * Ws_[k];
  }
  float* accum = ws + cur;  // 7*16 = 112 floats

  hipMemsetAsync(accum, 0, 112*sizeof(float), stream);

  const int n = 16*512*512;
  gamma_kernel<<<(2*n+255)/256, 256, 0, stream>>>(h, l, ws + off[0], n);

  for (int k=0;k<6;k++){
    int total = 32*Hs[k+1]*Ws_[k+1];
    down_kernel<<<(total+255)/256, 256, 0, stream>>>(
        ws+off[k], ws+off[k+1], Hs[k], Ws_[k], Hs[k+1], Ws_[k+1]);
  }
  for (int k=0;k<6;k++){
    int total = 32*Hs[k]*Ws_[k];
    lap_kernel<<<(total+255)/256, 256, 0, stream>>>(
        ws+off[k], ws+off[k+1], Hs[k], Ws_[k]);
  }
  for (int k=0;k<7;k++){
    int HW = Hs[k]*Ws_[k];
    dim3 grid((HW+255)/256, 16);
    normdiff_kernel<<<grid, 256, 0, stream>>>(
        ws+off[k], accum, Hs[k], Ws_[k], k, (k==6)?1:0);
  }
  finalize_kernel<<<1, 64, 0, stream>>>(accum, out);
}

// Round 3
// 237.458 us; speedup vs baseline: 1.8226x; 1.8226x over previous
//
#include <hip/hip_runtime.h>

#define SIG0 0.17f
#define SIG1 4.86f

__device__ __constant__ float c_filt0[25] = {
  0.04f,0.04f,0.05f,0.04f,0.04f,
  0.04f,0.03f,0.04f,0.03f,0.04f,
  0.05f,0.04f,0.05f,0.04f,0.05f,
  0.04f,0.03f,0.04f,0.03f,0.04f,
  0.04f,0.04f,0.05f,0.04f,0.04f};

static __device__ __forceinline__ int iclamp(int v, int lo, int hi){
  return v < lo ? lo : (v > hi ? hi : v);
}

// ---------------- gamma: out[0:n) = h^(1/2.6), out[n:2n) = l^(1/2.6), float4 ----------------
__global__ __launch_bounds__(256)
void gamma_kernel(const float4* __restrict__ h, const float4* __restrict__ l,
                  float4* __restrict__ out, int n4){
  int i = blockIdx.x*blockDim.x + threadIdx.x;
  if (i >= 2*n4) return;
  float4 v = (i < n4) ? h[i] : l[i-n4];
  const float e = 0.3846153846153846f;
  v.x = __powf(v.x, e); v.y = __powf(v.y, e);
  v.z = __powf(v.z, e); v.w = __powf(v.w, e);
  out[i] = v;
}

// ---------------- down: LDS-staged separable 5-tap, stride 2 ----------------
// output tile 64x16, block 256. grid (ceil(Wo/64), ceil(Ho/16), 32)
#define DTW 132
#define DTH 36
__global__ __launch_bounds__(256)
void down_kernel(const float* __restrict__ in, float* __restrict__ out,
                 int H, int W, int Ho, int Wo){
  int xo0 = blockIdx.x*64, yo0 = blockIdx.y*16, b = blockIdx.z;
  int tid = threadIdx.x;
  __shared__ float st[DTH][DTW];
  __shared__ float hs[DTH][64];
  const float* ip = in + (size_t)b*H*W;
  for (int f = tid; f < DTH*DTW; f += 256){
    int r = f / DTW, c = f % DTW;
    int yy = iclamp(2*yo0 - 2 + r, 0, H-1);
    int xx = iclamp(2*xo0 - 2 + c, 0, W-1);
    st[r][c] = ip[(size_t)yy*W + xx];
  }
  __syncthreads();
  for (int f = tid; f < DTH*64; f += 256){
    int r = f >> 6, xo = f & 63;
    const float* rp = st[r] + 2*xo;
    hs[r][xo] = 0.05f*rp[0] + 0.25f*rp[1] + 0.4f*rp[2] + 0.25f*rp[3] + 0.05f*rp[4];
  }
  __syncthreads();
  for (int f = tid; f < 16*64; f += 256){
    int yo = f >> 6, xo = f & 63;
    int X = xo0 + xo, Y = yo0 + yo;
    if (X < Wo && Y < Ho){
      out[(size_t)b*Ho*Wo + (size_t)Y*Wo + X] =
        0.05f*hs[2*yo][xo] + 0.25f*hs[2*yo+1][xo] + 0.4f*hs[2*yo+2][xo]
      + 0.25f*hs[2*yo+3][xo] + 0.05f*hs[2*yo+4][xo];
    }
  }
}

// ---------------- fused lap + normalize + diff + reduce (levels 0..5) ----------------
// output tile 64x16 per block, both images (b and b+16) in one block.
// grid (ceil(W/64), ceil(H/16), 16)
#define OTW 64
#define OTH 16
#define TW 68
#define TWP 69   // padded stride: 69 mod 32 = 5 -> 2-way conflicts only (free)
#define TH 20
#define GW 36
#define GH 12
__global__ __launch_bounds__(256)
void fused_kernel(const float* __restrict__ g0, const float* __restrict__ g1,
                  float* __restrict__ accum, int H, int W, int lev){
  int Hg = H>>1, Wg = W>>1;
  int x0 = blockIdx.x * OTW;
  int y0 = blockIdx.y * OTH;
  int b  = blockIdx.z;
  int tid = threadIdx.x;

  __shared__ float sg[2][TH][TWP];   // g_k tile, overwritten in-place by lap
  __shared__ float s1[2][GH][GW];    // g_{k+1} tile
  __shared__ float swave[4];

  const float* g0p0 = g0 + (size_t)b*H*W;
  const float* g0p1 = g0 + (size_t)(b+16)*H*W;
  const float* g1p0 = g1 + (size_t)b*Hg*Wg;
  const float* g1p1 = g1 + (size_t)(b+16)*Hg*Wg;

  int gy0 = (y0>>1) - 2, gx0 = (x0>>1) - 2;

  // phase 1: load tiles (coalesced, clamped)
  for (int f = tid; f < 2*TH*TW; f += 256){
    int img = f / (TH*TW);
    int rem = f % (TH*TW);
    int r = rem / TW, c = rem % TW;
    int yy = iclamp(y0 - 2 + r, 0, H-1);
    int xx = iclamp(x0 - 2 + c, 0, W-1);
    const float* p = img ? g0p1 : g0p0;
    sg[img][r][c] = p[(size_t)yy*W + xx];
  }
  for (int f = tid; f < 2*GH*GW; f += 256){
    int img = f / (GH*GW);
    int rem = f % (GH*GW);
    int r = rem / GW, c = rem % GW;
    int yy = iclamp(gy0 + r, 0, Hg-1);
    int xx = iclamp(gx0 + c, 0, Wg-1);
    const float* p = img ? g1p1 : g1p0;
    s1[img][r][c] = p[(size_t)yy*Wg + xx];
  }
  __syncthreads();

  // phase 2: lap in place: sg -= up(g1)   (each thread RMWs only its own slots)
  for (int f = tid; f < 2*TH*TW; f += 256){
    int img = f / (TH*TW);
    int rem = f % (TH*TW);
    int r = rem / TW, c = rem % TW;
    int yy = iclamp(y0 - 2 + r, 0, H-1);
    int xx = iclamp(x0 - 2 + c, 0, W-1);
    int y2 = yy>>1, x2 = xx>>1;
    int ry0, ry1, ry2; float wy0, wy1, wy2;
    if ((yy&1)==0){
      ry0=iclamp(y2-1,0,Hg-1); ry1=y2; ry2=iclamp(y2+1,0,Hg-1);
      wy0=0.2f; wy1=1.6f; wy2=0.2f;            // 4 * {0.05,0.4,0.05}
    } else {
      ry0=y2; ry1=iclamp(y2+1,0,Hg-1); ry2=y2;
      wy0=1.0f; wy1=1.0f; wy2=0.0f;            // 4 * {0.25,0.25}
    }
    int cx0, cx1, cx2; float wx0, wx1, wx2;
    if ((xx&1)==0){
      cx0=iclamp(x2-1,0,Wg-1); cx1=x2; cx2=iclamp(x2+1,0,Wg-1);
      wx0=0.05f; wx1=0.4f; wx2=0.05f;
    } else {
      cx0=x2; cx1=iclamp(x2+1,0,Wg-1); cx2=x2;
      wx0=0.25f; wx1=0.25f; wx2=0.0f;
    }
    ry0-=gy0; ry1-=gy0; ry2-=gy0; cx0-=gx0; cx1-=gx0; cx2-=gx0;
    const float (*sp)[GW] = s1[img];
    float u0 = wx0*sp[ry0][cx0] + wx1*sp[ry0][cx1] + wx2*sp[ry0][cx2];
    float u1 = wx0*sp[ry1][cx0] + wx1*sp[ry1][cx1] + wx2*sp[ry1][cx2];
    float u2 = wx0*sp[ry2][cx0] + wx1*sp[ry2][cx1] + wx2*sp[ry2][cx2];
    sg[img][r][c] -= wy0*u0 + wy1*u1 + wy2*u2;
  }
  __syncthreads();

  // phase 3: denominator conv + normalized diff + reduce. 4 outputs/thread.
  int tx = tid & 15, ty = tid >> 4;
  int xl = tx * 4;
  float v = 0.f;
  {
    float numh[4], denh[4], numl[4], denl[4];
    #pragma unroll
    for (int j=0;j<4;j++){ denh[j]=SIG0; denl[j]=SIG0; }
    #pragma unroll
    for (int i=0;i<5;i++){
      float r_[8];
      #pragma unroll
      for (int j=0;j<8;j++) r_[j] = sg[0][ty+i][xl+j];
      if (i==2){ numh[0]=r_[2]; numh[1]=r_[3]; numh[2]=r_[4]; numh[3]=r_[5]; }
      #pragma unroll
      for (int j=0;j<8;j++) r_[j] = fabsf(r_[j]);
      #pragma unroll
      for (int jj=0;jj<5;jj++){
        float w = c_filt0[i*5+jj];
        denh[0]+=w*r_[jj]; denh[1]+=w*r_[jj+1]; denh[2]+=w*r_[jj+2]; denh[3]+=w*r_[jj+3];
      }
    }
    #pragma unroll
    for (int i=0;i<5;i++){
      float r_[8];
      #pragma unroll
      for (int j=0;j<8;j++) r_[j] = sg[1][ty+i][xl+j];
      if (i==2){ numl[0]=r_[2]; numl[1]=r_[3]; numl[2]=r_[4]; numl[3]=r_[5]; }
      #pragma unroll
      for (int j=0;j<8;j++) r_[j] = fabsf(r_[j]);
      #pragma unroll
      for (int jj=0;jj<5;jj++){
        float w = c_filt0[i*5+jj];
        denl[0]+=w*r_[jj]; denl[1]+=w*r_[jj+1]; denl[2]+=w*r_[jj+2]; denl[3]+=w*r_[jj+3];
      }
    }
    int yglob = y0 + ty;
    #pragma unroll
    for (int j=0;j<4;j++){
      int xglob = x0 + xl + j;
      if (yglob < H && xglob < W){
        float d = numh[j]/denh[j] - numl[j]/denl[j];
        v += d*d;
      }
    }
  }
  #pragma unroll
  for (int off=32; off>0; off>>=1) v += __shfl_down(v, off);
  if ((tid & 63) == 0) swave[tid>>6] = v;
  __syncthreads();
  if (tid == 0){
    float s = swave[0]+swave[1]+swave[2]+swave[3];
    atomicAdd(&accum[lev*16 + b], s);
  }
}

// ---------------- last level (k=6, 8x8): den = |x| + SIG1 ----------------
__global__ __launch_bounds__(1024)
void last_kernel(const float* __restrict__ g6, float* __restrict__ accum){
  int tid = threadIdx.x;
  int b = tid >> 6, p = tid & 63;
  float ch = g6[(size_t)b*64 + p];
  float cl = g6[(size_t)(b+16)*64 + p];
  float d = ch/(fabsf(ch)+SIG1) - cl/(fabsf(cl)+SIG1);
  float v = d*d;
  #pragma unroll
  for (int off=32; off>0; off>>=1) v += __shfl_down(v, off);
  if (p == 0) accum[6*16 + b] = v;
}

// ---------------- finalize ----------------
__global__ __launch_bounds__(64)
void finalize_kernel(const float* __restrict__ accum, float* __restrict__ out){
  __shared__ float s[16];
  int b = threadIdx.x;
  if (b < 16){
    float m = 0.f;
    #pragma unroll
    for (int k=0;k<7;k++){
      int hw = (512>>k)*(512>>k);
      float mean = accum[k*16+b] / (float)hw;
      m += powf(mean, 0.3f);             // EXP_F/EXP_S
    }
    m *= (1.0f/7.0f);
    s[b] = powf(m, 1.6666666666666667f); // 1/EXP_F
  }
  __syncthreads();
  if (b == 0){
    float t = 0.f;
    #pragma unroll
    for (int i=0;i<16;i++) t += s[i];
    out[0] = t * (1.0f/16.0f);
  }
}

extern "C" void kernel_launch(void* const* d_in, const int* in_sizes, int n_in,
                              void* d_out, int out_size, void* d_ws, size_t ws_size,
                              hipStream_t stream){
  const float* h = (const float*)d_in[0];
  const float* l = (const float*)d_in[1];
  float* out = (float*)d_out;
  float* ws = (float*)d_ws;

  int Hs[7];
  size_t off[7];
  size_t cur = 0;
  for (int k=0;k<7;k++){
    Hs[k] = 512 >> k;
    off[k] = cur;
    cur += (size_t)32 * Hs[k] * Hs[k];
  }
  float* accum = ws + cur;  // 112 floats

  hipMemsetAsync(accum, 0, 112*sizeof(float), stream);

  const int n4 = 16*512*512/4;
  gamma_kernel<<<(2*n4+255)/256, 256, 0, stream>>>(
      (const float4*)h, (const float4*)l, (float4*)(ws + off[0]), n4);

  for (int k=0;k<6;k++){
    int Ho = Hs[k+1];
    dim3 grid((Ho+63)/64, (Ho+15)/16, 32);
    down_kernel<<<grid, 256, 0, stream>>>(ws+off[k], ws+off[k+1], Hs[k], Hs[k], Ho, Ho);
  }
  for (int k=0;k<6;k++){
    int H = Hs[k];
    dim3 grid((H+63)/64, (H+15)/16, 16);
    fused_kernel<<<grid, 256, 0, stream>>>(ws+off[k], ws+off[k+1], accum, H, H, k);
  }
  last_kernel<<<1, 1024, 0, stream>>>(ws+off[6], accum);
  finalize_kernel<<<1, 64, 0, stream>>>(accum, out);
}

// Round 4
// 195.537 us; speedup vs baseline: 2.2134x; 1.2144x over previous
//
#include <hip/hip_runtime.h>

#define SIG0 0.17f
#define SIG1 4.86f

__device__ __constant__ float c_filt0[25] = {
  0.04f,0.04f,0.05f,0.04f,0.04f,
  0.04f,0.03f,0.04f,0.03f,0.04f,
  0.05f,0.04f,0.05f,0.04f,0.05f,
  0.04f,0.03f,0.04f,0.03f,0.04f,
  0.04f,0.04f,0.05f,0.04f,0.04f};
__device__ __constant__ float c_f1d[5] = {0.05f,0.25f,0.4f,0.25f,0.05f};

static __device__ __forceinline__ int iclamp(int v, int lo, int hi){
  return v < lo ? lo : (v > hi ? hi : v);
}

// ================= down0 + gamma fused: reads raw input, writes g0 (gamma'd) and g1 =================
// fixed 512x512 -> 256x256, g1 tile 64x16 per block, grid (4,16,32), z = image index (0..15 h, 16..31 l)
#define D0W 136
#define D0H 36
__global__ __launch_bounds__(256)
void down0_gamma(const float* __restrict__ hin, const float* __restrict__ lin,
                 float* __restrict__ g0, float* __restrict__ g1){
  const int H=512, W=512, Wo=256;
  int xo0 = blockIdx.x*64, yo0 = blockIdx.y*16;
  int z = blockIdx.z;
  const float* in = (z<16) ? (hin + (size_t)z*H*W) : (lin + (size_t)(z-16)*H*W);
  int tid = threadIdx.x;
  __shared__ float st[D0H][D0W];
  __shared__ float hs[D0H][64];
  const float e = 0.3846153846153846f;
  for (int f=tid; f<D0H*D0W; f+=256){
    int r=f/D0W, c=f%D0W;
    int yy=iclamp(2*yo0-2+r,0,H-1);
    int xx=iclamp(2*xo0-4+c,0,W-1);
    st[r][c] = __powf(in[(size_t)yy*W+xx], e);
  }
  __syncthreads();
  // write g0 interior: rows 2..33 <-> global 2yo0..2yo0+31, cols 4..131 <-> 2xo0..2xo0+127
  float* g0p = g0 + (size_t)z*H*W;
  for (int f=tid; f<32*32; f+=256){
    int r=f>>5, q=f&31;
    float4 v = *(const float4*)&st[2+r][4+4*q];
    *(float4*)&g0p[(size_t)(2*yo0+r)*W + 2*xo0 + 4*q] = v;
  }
  // horizontal pass: hs[r][xo] over cols 2*xo+2..2*xo+6
  for (int f=tid; f<D0H*64; f+=256){
    int r=f>>6, xo=f&63;
    const float* rp = &st[r][2*xo+2];
    hs[r][xo] = 0.05f*rp[0]+0.25f*rp[1]+0.4f*rp[2]+0.25f*rp[3]+0.05f*rp[4];
  }
  __syncthreads();
  float* g1p = g1 + (size_t)z*Wo*Wo;
  for (int f=tid; f<16*64; f+=256){
    int yo=f>>6, xo=f&63;
    g1p[(size_t)(yo0+yo)*Wo + xo0+xo] =
      0.05f*hs[2*yo][xo]+0.25f*hs[2*yo+1][xo]+0.4f*hs[2*yo+2][xo]
     +0.25f*hs[2*yo+3][xo]+0.05f*hs[2*yo+4][xo];
  }
}

// ================= generic down (levels 1,2) — proven round-3 version =================
#define DTW 132
#define DTH 36
__global__ __launch_bounds__(256)
void down_kernel(const float* __restrict__ in, float* __restrict__ out,
                 int H, int W, int Ho, int Wo){
  int xo0 = blockIdx.x*64, yo0 = blockIdx.y*16, b = blockIdx.z;
  int tid = threadIdx.x;
  __shared__ float st[DTH][DTW];
  __shared__ float hs[DTH][64];
  const float* ip = in + (size_t)b*H*W;
  for (int f = tid; f < DTH*DTW; f += 256){
    int r = f / DTW, c = f % DTW;
    int yy = iclamp(2*yo0 - 2 + r, 0, H-1);
    int xx = iclamp(2*xo0 - 2 + c, 0, W-1);
    st[r][c] = ip[(size_t)yy*W + xx];
  }
  __syncthreads();
  for (int f = tid; f < DTH*64; f += 256){
    int r = f >> 6, xo = f & 63;
    const float* rp = st[r] + 2*xo;
    hs[r][xo] = 0.05f*rp[0] + 0.25f*rp[1] + 0.4f*rp[2] + 0.25f*rp[3] + 0.05f*rp[4];
  }
  __syncthreads();
  for (int f = tid; f < 16*64; f += 256){
    int yo = f >> 6, xo = f & 63;
    int X = xo0 + xo, Y = yo0 + yo;
    if (X < Wo && Y < Ho){
      out[(size_t)b*Ho*Wo + (size_t)Y*Wo + X] =
        0.05f*hs[2*yo][xo] + 0.25f*hs[2*yo+1][xo] + 0.4f*hs[2*yo+2][xo]
      + 0.25f*hs[2*yo+3][xo] + 0.05f*hs[2*yo+4][xo];
    }
  }
}

// ================= fused lap + normalize + diff + reduce (levels 0..2) =================
#define FTW 72
#define FTH 20
#define FGW 40
#define FGH 12

static __device__ __forceinline__ float4 rowi(const float* p){
  float4 t;
  t.x = 0.05f*p[0] + 0.4f*p[1] + 0.05f*p[2];
  t.y = 0.25f*(p[1]+p[2]);
  t.z = 0.05f*p[1] + 0.4f*p[2] + 0.05f*p[3];
  t.w = 0.25f*(p[2]+p[3]);
  return t;
}

__global__ __launch_bounds__(256)
void fused_kernel(const float* __restrict__ g0, const float* __restrict__ g1,
                  float* __restrict__ accum, int H, int W, int lev){
  int Hg=H>>1, Wg=W>>1;
  int x0 = blockIdx.x*64, y0 = blockIdx.y*16, b = blockIdx.z;
  int tid = threadIdx.x;
  bool edge = (blockIdx.x==0) || (blockIdx.x==gridDim.x-1) ||
              (blockIdx.y==0) || (blockIdx.y==gridDim.y-1);

  __shared__ float sg[2][FTH][FTW];   // g_k tile (cols x0-4 .. x0+67), becomes lap in place
  __shared__ float s1[2][FGH][FGW];   // g_{k+1} tile (cols gx0 .. gx0+39)
  __shared__ float swave[4];

  const float* g0b0 = g0 + (size_t)b*H*W;
  const float* g0b1 = g0 + (size_t)(b+16)*H*W;
  const float* g1b0 = g1 + (size_t)b*Hg*Wg;
  const float* g1b1 = g1 + (size_t)(b+16)*Hg*Wg;
  int gy0 = (y0>>1)-2, gx0 = (x0>>1)-4;

  if (!edge){
    // ---- interior: float4 staging, no clamps ----
    for (int f=tid; f<2*FTH*18; f+=256){
      int img=f/360, rem=f%360, r=rem/18, q=rem%18;
      const float* src = img ? g0b1 : g0b0;
      *(float4*)&sg[img][r][4*q] = *(const float4*)&src[(size_t)(y0-2+r)*W + x0-4+4*q];
    }
    for (int f=tid; f<2*FGH*10; f+=256){
      int img=f/120, rem=f%120, r=rem/10, q=rem%10;
      const float* src = img ? g1b1 : g1b0;
      *(float4*)&s1[img][r][4*q] = *(const float4*)&src[(size_t)(gy0+r)*Wg + gx0+4*q];
    }
    __syncthreads();
    // ---- phase 2: lap in place, float4 chunks, compile-time parity ----
    for (int f=tid; f<2*FTH*18; f+=256){
      int img=f/360, rem=f%360, r=rem/18, q=rem%18;
      int ry = ((r-2)>>1) + 2;   // local row of y2 in s1
      int cb = 2*q+1;            // local col of x2-1 in s1
      float4 u;
      if ((r&1)==0){
        float4 a = rowi(&s1[img][ry-1][cb]);
        float4 m = rowi(&s1[img][ry  ][cb]);
        float4 c2 = rowi(&s1[img][ry+1][cb]);
        u.x = 0.2f*a.x + 1.6f*m.x + 0.2f*c2.x;
        u.y = 0.2f*a.y + 1.6f*m.y + 0.2f*c2.y;
        u.z = 0.2f*a.z + 1.6f*m.z + 0.2f*c2.z;
        u.w = 0.2f*a.w + 1.6f*m.w + 0.2f*c2.w;
      } else {
        float4 a = rowi(&s1[img][ry  ][cb]);
        float4 m = rowi(&s1[img][ry+1][cb]);
        u.x = a.x + m.x; u.y = a.y + m.y; u.z = a.z + m.z; u.w = a.w + m.w;
      }
      float4 val = *(float4*)&sg[img][r][4*q];
      val.x -= u.x; val.y -= u.y; val.z -= u.z; val.w -= u.w;
      *(float4*)&sg[img][r][4*q] = val;
    }
  } else {
    // ---- edge: scalar clamped path (proven) ----
    for (int f=tid; f<2*FTH*FTW; f+=256){
      int img=f/(FTH*FTW), rem=f%(FTH*FTW), r=rem/FTW, c=rem%FTW;
      int yy=iclamp(y0-2+r,0,H-1), xx=iclamp(x0-4+c,0,W-1);
      const float* src = img ? g0b1 : g0b0;
      sg[img][r][c] = src[(size_t)yy*W+xx];
    }
    for (int f=tid; f<2*FGH*FGW; f+=256){
      int img=f/(FGH*FGW), rem=f%(FGH*FGW), r=rem/FGW, c=rem%FGW;
      int yy=iclamp(gy0+r,0,Hg-1), xx=iclamp(gx0+c,0,Wg-1);
      const float* src = img ? g1b1 : g1b0;
      s1[img][r][c] = src[(size_t)yy*Wg+xx];
    }
    __syncthreads();
    for (int f=tid; f<2*FTH*FTW; f+=256){
      int img=f/(FTH*FTW), rem=f%(FTH*FTW), r=rem/FTW, c=rem%FTW;
      int yy=iclamp(y0-2+r,0,H-1), xx=iclamp(x0-4+c,0,W-1);
      int y2=yy>>1, x2=xx>>1;
      int ry0,ry1,ry2; float wy0,wy1,wy2;
      if ((yy&1)==0){
        ry0=iclamp(y2-1,0,Hg-1); ry1=y2; ry2=iclamp(y2+1,0,Hg-1);
        wy0=0.2f; wy1=1.6f; wy2=0.2f;
      } else {
        ry0=y2; ry1=iclamp(y2+1,0,Hg-1); ry2=y2;
        wy0=1.0f; wy1=1.0f; wy2=0.0f;
      }
      int cx0,cx1,cx2; float wx0,wx1,wx2;
      if ((xx&1)==0){
        cx0=iclamp(x2-1,0,Wg-1); cx1=x2; cx2=iclamp(x2+1,0,Wg-1);
        wx0=0.05f; wx1=0.4f; wx2=0.05f;
      } else {
        cx0=x2; cx1=iclamp(x2+1,0,Wg-1); cx2=x2;
        wx0=0.25f; wx1=0.25f; wx2=0.0f;
      }
      ry0-=gy0; ry1-=gy0; ry2-=gy0; cx0-=gx0; cx1-=gx0; cx2-=gx0;
      const float (*sp)[FGW] = s1[img];
      float u0 = wx0*sp[ry0][cx0] + wx1*sp[ry0][cx1] + wx2*sp[ry0][cx2];
      float u1 = wx0*sp[ry1][cx0] + wx1*sp[ry1][cx1] + wx2*sp[ry1][cx2];
      float u2 = wx0*sp[ry2][cx0] + wx1*sp[ry2][cx1] + wx2*sp[ry2][cx2];
      sg[img][r][c] -= wy0*u0 + wy1*u1 + wy2*u2;
    }
  }
  __syncthreads();

  // ---- phase 3: den conv + diff + reduce; 4 outputs/thread, float4 LDS reads ----
  int tx = tid & 15, ty = tid >> 4;
  int xl = tx*4;
  float denh[4], denl[4], numh[4], numl[4];
  #pragma unroll
  for (int j=0;j<4;j++){ denh[j]=SIG0; denl[j]=SIG0; }
  #pragma unroll
  for (int i=0;i<5;i++){
    float r_[12];
    *(float4*)&r_[0] = *(const float4*)&sg[0][ty+i][xl];
    *(float4*)&r_[4] = *(const float4*)&sg[0][ty+i][xl+4];
    *(float4*)&r_[8] = *(const float4*)&sg[0][ty+i][xl+8];
    if (i==2){ numh[0]=r_[4]; numh[1]=r_[5]; numh[2]=r_[6]; numh[3]=r_[7]; }
    #pragma unroll
    for (int jj=0;jj<5;jj++){
      float w = c_filt0[i*5+jj];
      #pragma unroll
      for (int j=0;j<4;j++) denh[j] += w*fabsf(r_[2+j+jj]);
    }
  }
  #pragma unroll
  for (int i=0;i<5;i++){
    float r_[12];
    *(float4*)&r_[0] = *(const float4*)&sg[1][ty+i][xl];
    *(float4*)&r_[4] = *(const float4*)&sg[1][ty+i][xl+4];
    *(float4*)&r_[8] = *(const float4*)&sg[1][ty+i][xl+8];
    if (i==2){ numl[0]=r_[4]; numl[1]=r_[5]; numl[2]=r_[6]; numl[3]=r_[7]; }
    #pragma unroll
    for (int jj=0;jj<5;jj++){
      float w = c_filt0[i*5+jj];
      #pragma unroll
      for (int j=0;j<4;j++) denl[j] += w*fabsf(r_[2+j+jj]);
    }
  }
  float v = 0.f;
  #pragma unroll
  for (int j=0;j<4;j++){
    float d = __fdividef(numh[j], denh[j]) - __fdividef(numl[j], denl[j]);
    v += d*d;
  }
  #pragma unroll
  for (int off=32; off>0; off>>=1) v += __shfl_down(v, off);
  if ((tid & 63) == 0) swave[tid>>6] = v;
  __syncthreads();
  if (tid == 0){
    float s = swave[0]+swave[1]+swave[2]+swave[3];
    atomicAdd(&accum[lev*16 + b], s);
  }
}

// ================= tail: levels 3..6 fully in LDS, one block per batch =================
static __device__ __forceinline__ void down_lds(const float* Ain, int ldi, int Sin,
                                                float* Aout, int ldo, int Sout,
                                                int tid, int NT){
  int tot = 2*Sout*Sout;
  for (int f=tid; f<tot; f+=NT){
    int img = f/(Sout*Sout), rem = f%(Sout*Sout), y=rem/Sout, x=rem%Sout;
    const float* A = Ain + img*Sin*ldi;
    float s=0.f;
    #pragma unroll
    for (int i=0;i<5;i++){
      int yy=iclamp(2*y+i-2,0,Sin-1);
      float rs=0.f;
      #pragma unroll
      for (int j=0;j<5;j++){
        int xx=iclamp(2*x+j-2,0,Sin-1);
        rs += c_f1d[j]*A[yy*ldi+xx];
      }
      s += c_f1d[i]*rs;
    }
    Aout[img*Sout*ldo + y*ldo + x] = s;
  }
}

static __device__ __forceinline__ void lap_lds(float* Ak, int ldk, int S,
                                               const float* Ag, int ldg,
                                               int tid, int NT){
  int Sg = S>>1;
  int tot = 2*S*S;
  for (int f=tid; f<tot; f+=NT){
    int img=f/(S*S), rem=f%(S*S), y=rem/S, x=rem%S;
    const float* G = Ag + img*Sg*ldg;
    int y2=y>>1, x2=x>>1;
    int ry0,ry1,ry2; float wy0,wy1,wy2;
    if (!(y&1)){ ry0=iclamp(y2-1,0,Sg-1); ry1=y2; ry2=iclamp(y2+1,0,Sg-1); wy0=0.2f; wy1=1.6f; wy2=0.2f; }
    else { ry0=y2; ry1=iclamp(y2+1,0,Sg-1); ry2=y2; wy0=1.f; wy1=1.f; wy2=0.f; }
    int cx0,cx1,cx2; float wx0,wx1,wx2;
    if (!(x&1)){ cx0=iclamp(x2-1,0,Sg-1); cx1=x2; cx2=iclamp(x2+1,0,Sg-1); wx0=0.05f; wx1=0.4f; wx2=0.05f; }
    else { cx0=x2; cx1=iclamp(x2+1,0,Sg-1); cx2=x2; wx0=0.25f; wx1=0.25f; wx2=0.f; }
    float u0 = wx0*G[ry0*ldg+cx0]+wx1*G[ry0*ldg+cx1]+wx2*G[ry0*ldg+cx2];
    float u1 = wx0*G[ry1*ldg+cx0]+wx1*G[ry1*ldg+cx1]+wx2*G[ry1*ldg+cx2];
    float u2 = wx0*G[ry2*ldg+cx0]+wx1*G[ry2*ldg+cx1]+wx2*G[ry2*ldg+cx2];
    Ak[img*S*ldk + y*ldk + x] -= wy0*u0+wy1*u1+wy2*u2;
  }
}

static __device__ __forceinline__ float diff_lds(const float* A, int ld, int S,
                                                 int tid, int NT){
  float v=0.f;
  const float* Ah = A;
  const float* Al = A + S*ld;
  for (int f=tid; f<S*S; f+=NT){
    int y=f/S, x=f%S;
    float dh=SIG0, dl=SIG0;
    #pragma unroll
    for (int i=0;i<5;i++){
      int yy=iclamp(y+i-2,0,S-1);
      #pragma unroll
      for (int j=0;j<5;j++){
        int xx=iclamp(x+j-2,0,S-1);
        float w=c_filt0[i*5+j];
        dh += w*fabsf(Ah[yy*ld+xx]);
        dl += w*fabsf(Al[yy*ld+xx]);
      }
    }
    float d = __fdividef(Ah[y*ld+x],dh) - __fdividef(Al[y*ld+x],dl);
    v += d*d;
  }
  return v;
}

__global__ __launch_bounds__(512)
void tail_kernel(const float* __restrict__ g3, float* __restrict__ accum){
  const int NT = 512;
  int b = blockIdx.x;
  int tid = threadIdx.x;
  __shared__ float A3[2][64][66];
  __shared__ float A4[2][32][34];
  __shared__ float A5[2][16][18];
  __shared__ float A6[2][8][10];
  __shared__ float sred[8];

  const float* s0 = g3 + (size_t)b*4096;
  const float* s1p = g3 + (size_t)(b+16)*4096;
  for (int f=tid; f<2*4096; f+=NT){
    int img=f>>12, rem=f&4095, r=rem>>6, c=rem&63;
    A3[img][r][c] = img ? s1p[rem] : s0[rem];
  }
  __syncthreads();
  down_lds(&A3[0][0][0], 66, 64, &A4[0][0][0], 34, 32, tid, NT);
  __syncthreads();
  down_lds(&A4[0][0][0], 34, 32, &A5[0][0][0], 18, 16, tid, NT);
  __syncthreads();
  down_lds(&A5[0][0][0], 18, 16, &A6[0][0][0], 10, 8, tid, NT);
  __syncthreads();
  lap_lds(&A3[0][0][0], 66, 64, &A4[0][0][0], 34, tid, NT);
  __syncthreads();
  float v3 = diff_lds(&A3[0][0][0], 66, 64, tid, NT);
  lap_lds(&A4[0][0][0], 34, 32, &A5[0][0][0], 18, tid, NT);
  __syncthreads();
  float v4 = diff_lds(&A4[0][0][0], 34, 32, tid, NT);
  lap_lds(&A5[0][0][0], 18, 16, &A6[0][0][0], 10, tid, NT);
  __syncthreads();
  float v5 = diff_lds(&A5[0][0][0], 18, 16, tid, NT);
  float v6 = 0.f;
  for (int f=tid; f<64; f+=NT){
    float ch = A6[0][f>>3][f&7];
    float cl = A6[1][f>>3][f&7];
    float d = __fdividef(ch, fabsf(ch)+SIG1) - __fdividef(cl, fabsf(cl)+SIG1);
    v6 += d*d;
  }
  // reductions
  float vs[4] = {v3, v4, v5, v6};
  #pragma unroll
  for (int k=0;k<4;k++){
    float v = vs[k];
    #pragma unroll
    for (int off=32; off>0; off>>=1) v += __shfl_down(v, off);
    if ((tid&63)==0) sred[tid>>6] = v;
    __syncthreads();
    if (tid==0){
      float s=0.f;
      #pragma unroll
      for (int w=0;w<8;w++) s += sred[w];
      accum[(3+k)*16 + b] = s;
    }
    __syncthreads();
  }
}

// ================= finalize =================
__global__ __launch_bounds__(64)
void finalize_kernel(const float* __restrict__ accum, float* __restrict__ out){
  __shared__ float s[16];
  int b = threadIdx.x;
  if (b < 16){
    float m = 0.f;
    #pragma unroll
    for (int k=0;k<7;k++){
      int hw = (512>>k)*(512>>k);
      float mean = accum[k*16+b] / (float)hw;
      m += powf(mean, 0.3f);
    }
    m *= (1.0f/7.0f);
    s[b] = powf(m, 1.6666666666666667f);
  }
  __syncthreads();
  if (b == 0){
    float t = 0.f;
    #pragma unroll
    for (int i=0;i<16;i++) t += s[i];
    out[0] = t * (1.0f/16.0f);
  }
}

extern "C" void kernel_launch(void* const* d_in, const int* in_sizes, int n_in,
                              void* d_out, int out_size, void* d_ws, size_t ws_size,
                              hipStream_t stream){
  const float* h = (const float*)d_in[0];
  const float* l = (const float*)d_in[1];
  float* out = (float*)d_out;
  float* ws = (float*)d_ws;

  size_t off0 = 0;
  size_t off1 = off0 + (size_t)32*512*512;
  size_t off2 = off1 + (size_t)32*256*256;
  size_t off3 = off2 + (size_t)32*128*128;
  size_t offA = off3 + (size_t)32*64*64;
  float* accum = ws + offA;  // 112 floats

  hipMemsetAsync(accum, 0, 112*sizeof(float), stream);

  down0_gamma<<<dim3(4,16,32), 256, 0, stream>>>(h, l, ws+off0, ws+off1);
  fused_kernel<<<dim3(8,32,16), 256, 0, stream>>>(ws+off0, ws+off1, accum, 512, 512, 0);
  down_kernel<<<dim3(2,8,32), 256, 0, stream>>>(ws+off1, ws+off2, 256, 256, 128, 128);
  fused_kernel<<<dim3(4,16,16), 256, 0, stream>>>(ws+off1, ws+off2, accum, 256, 256, 1);
  down_kernel<<<dim3(1,4,32), 256, 0, stream>>>(ws+off2, ws+off3, 128, 128, 64, 64);
  fused_kernel<<<dim3(2,8,16), 256, 0, stream>>>(ws+off2, ws+off3, accum, 128, 128, 2);
  tail_kernel<<<dim3(16), 512, 0, stream>>>(ws+off3, accum);
  finalize_kernel<<<1, 64, 0, stream>>>(accum, out);
}

// Round 5
// 174.250 us; speedup vs baseline: 2.4838x; 1.1222x over previous
//
#include <hip/hip_runtime.h>

#define SIG0 0.17f
#define SIG1 4.86f

__device__ __constant__ float c_filt0[25] = {
  0.04f,0.04f,0.05f,0.04f,0.04f,
  0.04f,0.03f,0.04f,0.03f,0.04f,
  0.05f,0.04f,0.05f,0.04f,0.05f,
  0.04f,0.03f,0.04f,0.03f,0.04f,
  0.04f,0.04f,0.05f,0.04f,0.04f};
__device__ __constant__ float c_f1d[5] = {0.05f,0.25f,0.4f,0.25f,0.05f};

static __device__ __forceinline__ int iclamp(int v, int lo, int hi){
  return v < lo ? lo : (v > hi ? hi : v);
}

// Padded level buffers: level size S stored as (S+4) rows x (S+8) cols,
// logical (y,x) at [(y+2)*(S+8) + (x+4)], apron = replicate of border.
// g1: S=256 PS=264 R=260 (img stride 68640)
// g2: S=128 PS=136 R=132 (img stride 17952)
// g3: S=64  PS=72  R=68  (img stride 4896)

// ---------------- shared-mem layouts ----------------
struct FS {                      // fused kernel
  float sg[2][36][76];           // lap tile: rows y0-2..y0+33, cols x0-4..x0+67
  float s1[2][20][44];           // g_{k+1} tile: rows y0/2-2.., cols x0/2-4.. (40 used)
  float red[4];
};
struct DS {                      // down kernel
  float st[36][136];             // in rows 2yo0-2..+33, cols 2xo0-4..+131
  float hs[36][64];
};
struct TS {                      // tail kernel
  float A3[2][64][66];
  float A4[2][32][34];
  float A5[2][16][18];
  float A6[2][8][10];
  float red[4];
};

// ================= down body: padded in -> padded out (out tile 64x16) =================
__device__ __forceinline__ void down_body(const float* __restrict__ in0, float* __restrict__ out0,
                                          int PSI, int PSO, int Sout, int xo0, int yo0, char* smem){
  DS* S = (DS*)smem;
  int tid = threadIdx.x;
  for (int f=tid; f<36*34; f+=256){
    int r=f/34, c4=f%34;
    *(float4*)&S->st[r][4*c4] = *(const float4*)&in0[(size_t)(2*yo0+r)*PSI + 2*xo0 + 4*c4];
  }
  __syncthreads();
  for (int f=tid; f<36*64; f+=256){
    int r=f>>6, xo=f&63;
    const float* rp = &S->st[r][2*xo+2];
    S->hs[r][xo] = 0.05f*rp[0]+0.25f*rp[1]+0.4f*rp[2]+0.25f*rp[3]+0.05f*rp[4];
  }
  __syncthreads();
  for (int f=tid; f<16*64; f+=256){
    int yo=f>>6, xo=f&63;
    int Y=yo0+yo, X=xo0+xo;
    float v = 0.05f*S->hs[2*yo][xo]+0.25f*S->hs[2*yo+1][xo]+0.4f*S->hs[2*yo+2][xo]
            +0.25f*S->hs[2*yo+3][xo]+0.05f*S->hs[2*yo+4][xo];
    int rlo=(Y==0)?0:(Y+2), rhi=(Y==Sout-1)?(Sout+3):(Y+2);
    int clo=(X==0)?0:(X+4), chi=(X==Sout-1)?(Sout+7):(X+4);
    for (int rr=rlo; rr<=rhi; rr++)
      for (int cc=clo; cc<=chi; cc++)
        out0[(size_t)rr*PSO+cc] = v;
  }
}

// ================= k_d1: gamma + down0 (raw input -> padded g1) =================
__global__ __launch_bounds__(256)
void k_d1(const float* __restrict__ hin, const float* __restrict__ lin,
          float* __restrict__ g1){
  __shared__ DS S;
  int xo0 = blockIdx.x*64, yo0 = blockIdx.y*16, z = blockIdx.z;
  const float* in = (z<16)? hin + (size_t)z*262144 : lin + (size_t)(z-16)*262144;
  float* out0 = g1 + (size_t)z*68640;
  int tid = threadIdx.x;
  const float e = 0.3846153846153846f;
  for (int f=tid; f<36*34; f+=256){
    int r=f/34, c4=f%34;
    int yy = iclamp(2*yo0-2+r, 0, 511);
    int xb = 2*xo0-4+4*c4;
    const float* rp = in + (size_t)yy*512;
    float4 v;
    if (xb>=0 && xb<=508) v = *(const float4*)&rp[xb];
    else { v.x=rp[iclamp(xb,0,511)]; v.y=rp[iclamp(xb+1,0,511)];
           v.z=rp[iclamp(xb+2,0,511)]; v.w=rp[iclamp(xb+3,0,511)]; }
    v.x=__powf(v.x,e); v.y=__powf(v.y,e); v.z=__powf(v.z,e); v.w=__powf(v.w,e);
    *(float4*)&S.st[r][4*c4] = v;
  }
  __syncthreads();
  for (int f=tid; f<36*64; f+=256){
    int r=f>>6, xo=f&63;
    const float* rp = &S.st[r][2*xo+2];
    S.hs[r][xo] = 0.05f*rp[0]+0.25f*rp[1]+0.4f*rp[2]+0.25f*rp[3]+0.05f*rp[4];
  }
  __syncthreads();
  for (int f=tid; f<16*64; f+=256){
    int yo=f>>6, xo=f&63;
    int Y=yo0+yo, X=xo0+xo;
    float v = 0.05f*S.hs[2*yo][xo]+0.25f*S.hs[2*yo+1][xo]+0.4f*S.hs[2*yo+2][xo]
            +0.25f*S.hs[2*yo+3][xo]+0.05f*S.hs[2*yo+4][xo];
    int rlo=(Y==0)?0:(Y+2), rhi=(Y==255)?259:(Y+2);
    int clo=(X==0)?0:(X+4), chi=(X==255)?263:(X+4);
    for (int rr=rlo; rr<=rhi; rr++)
      for (int cc=clo; cc<=chi; cc++)
        out0[(size_t)rr*264+cc] = v;
  }
}

// ================= fused staging =================
__device__ __forceinline__ void fused_stage_s1(FS* S, const float* __restrict__ g10,
                                               const float* __restrict__ g11,
                                               int PS1, int x0, int y0){
  int tid = threadIdx.x;
  for (int f=tid; f<2*20*10; f+=256){
    int img=f/200, rem=f%200, ro=rem/10, co=rem%10;
    const float* src = img? g11 : g10;
    *(float4*)&S->s1[img][ro][4*co] = *(const float4*)&src[(size_t)(y0/2+ro)*PS1 + x0/2 + 4*co];
  }
}

__device__ __forceinline__ void fused_stage_g(FS* S, const float* __restrict__ gk0,
                                              const float* __restrict__ gk1,
                                              int PS0, int x0, int y0){
  int tid = threadIdx.x;
  for (int f=tid; f<2*36*18; f+=256){
    int img=f/648, rem=f%648, r=rem/18, q=rem%18;
    const float* src = img? gk1 : gk0;
    *(float4*)&S->sg[img][r][4*q] = *(const float4*)&src[(size_t)(y0+r)*PS0 + x0 + 4*q];
  }
}

__device__ __forceinline__ void fused_stage_in(FS* S, const float* __restrict__ h0,
                                               const float* __restrict__ l0,
                                               int x0, int y0){
  int tid = threadIdx.x;
  const float e = 0.3846153846153846f;
  for (int f=tid; f<2*36*18; f+=256){
    int img=f/648, rem=f%648, r=rem/18, q=rem%18;
    const float* src = img? l0 : h0;
    int yy = iclamp(y0-2+r, 0, 511);
    int xb = x0-4+4*q;
    const float* rp = src + (size_t)yy*512;
    float4 v;
    if (xb>=0 && xb<=508) v = *(const float4*)&rp[xb];
    else { v.x=rp[iclamp(xb,0,511)]; v.y=rp[iclamp(xb+1,0,511)];
           v.z=rp[iclamp(xb+2,0,511)]; v.w=rp[iclamp(xb+3,0,511)]; }
    v.x=__powf(v.x,e); v.y=__powf(v.y,e); v.z=__powf(v.z,e); v.w=__powf(v.w,e);
    *(float4*)&S->sg[img][r][4*q] = v;
  }
}

// up_row: horizontal upsample taps for one s1 row, f4-chunk base col cq=2q
__device__ __forceinline__ float4 up_row(const float* __restrict__ p){
  float2 A = *(const float2*)p;
  float2 B = *(const float2*)(p+2);
  float2 C = *(const float2*)(p+4);
  float4 t;
  t.x = 0.05f*A.y + 0.4f*B.x + 0.05f*B.y;
  t.y = 0.25f*(B.x+B.y);
  t.z = 0.05f*B.x + 0.4f*B.y + 0.05f*C.x;
  t.w = 0.25f*(B.y+C.x);
  return t;
}

// ================= fused tail: lap + replicate-fix + den conv + diff + reduce =================
__device__ __forceinline__ void fused_tail(FS* S, int Simg, int x0, int y0,
                                           float* __restrict__ accum, int lev, int b){
  int tid = threadIdx.x;
  __syncthreads();   // staging complete

  // p2: lap in place. sg row r <-> image row y0-2+r (parity of r, y0 even).
  for (int f=tid; f<2*36*18; f+=256){
    int img=f/648, rem=f%648, r=rem/18, q=rem%18;
    int ry = ((r-2)>>1)+2;
    int cq = 2*q;
    float4 u;
    if ((r&1)==0){
      float4 a = up_row(&S->s1[img][ry-1][cq]);
      float4 m = up_row(&S->s1[img][ry  ][cq]);
      float4 c2= up_row(&S->s1[img][ry+1][cq]);
      u.x = 0.2f*a.x+1.6f*m.x+0.2f*c2.x;
      u.y = 0.2f*a.y+1.6f*m.y+0.2f*c2.y;
      u.z = 0.2f*a.z+1.6f*m.z+0.2f*c2.z;
      u.w = 0.2f*a.w+1.6f*m.w+0.2f*c2.w;
    } else {
      float4 a = up_row(&S->s1[img][ry  ][cq]);
      float4 m = up_row(&S->s1[img][ry+1][cq]);
      u.x=a.x+m.x; u.y=a.y+m.y; u.z=a.z+m.z; u.w=a.w+m.w;
    }
    float4 val = *(float4*)&S->sg[img][r][4*q];
    val.x-=u.x; val.y-=u.y; val.z-=u.z; val.w-=u.w;
    *(float4*)&S->sg[img][r][4*q] = val;
  }
  __syncthreads();

  // replicate fix-up: apron rows/cols of lap tile = replicate of border lap
  bool top=(y0==0), bot=(y0+32==Simg), lft=(x0==0), rgt=(x0+64==Simg);
  if (top||bot||lft||rgt){
    for (int f=tid; f<2*18; f+=256){
      int img=f/18, q=f%18;
      if (top){ float4 v=*(float4*)&S->sg[img][2][4*q];
                *(float4*)&S->sg[img][0][4*q]=v; *(float4*)&S->sg[img][1][4*q]=v; }
      if (bot){ float4 v=*(float4*)&S->sg[img][33][4*q];
                *(float4*)&S->sg[img][34][4*q]=v; *(float4*)&S->sg[img][35][4*q]=v; }
    }
    __syncthreads();
    for (int f=tid; f<2*36; f+=256){
      int img=f/36, r=f%36;
      if (lft){ float v=S->sg[img][r][4];  float4 vv={v,v,v,v}; *(float4*)&S->sg[img][r][0]=vv; }
      if (rgt){ float v=S->sg[img][r][67]; float4 vv={v,v,v,v}; *(float4*)&S->sg[img][r][68]=vv; }
    }
    __syncthreads();
  }

  // p3: den conv + normalized diff, 8 outputs/thread (4 wide x 2 tall)
  int tx = tid & 15, ty = tid >> 4;
  int xl = 4*tx;
  float vacc = 0.f;
  float q0o0[4], q0o1[4];
  #pragma unroll
  for (int img=0; img<2; img++){
    float d0[4]={SIG0,SIG0,SIG0,SIG0}, d1[4]={SIG0,SIG0,SIG0,SIG0};
    float n0[4], n1[4];
    #pragma unroll
    for (int i=0;i<6;i++){
      float r_[12];
      *(float4*)&r_[0] = *(const float4*)&S->sg[img][2*ty+i][xl];
      *(float4*)&r_[4] = *(const float4*)&S->sg[img][2*ty+i][xl+4];
      *(float4*)&r_[8] = *(const float4*)&S->sg[img][2*ty+i][xl+8];
      if (i==2){ n0[0]=r_[4]; n0[1]=r_[5]; n0[2]=r_[6]; n0[3]=r_[7]; }
      if (i==3){ n1[0]=r_[4]; n1[1]=r_[5]; n1[2]=r_[6]; n1[3]=r_[7]; }
      if (i<5){
        #pragma unroll
        for (int jj=0;jj<5;jj++){
          float w = c_filt0[i*5+jj];
          #pragma unroll
          for (int j=0;j<4;j++) d0[j] += w*fabsf(r_[2+j+jj]);
        }
      }
      if (i>0){
        #pragma unroll
        for (int jj=0;jj<5;jj++){
          float w = c_filt0[(i-1)*5+jj];
          #pragma unroll
          for (int j=0;j<4;j++) d1[j] += w*fabsf(r_[2+j+jj]);
        }
      }
    }
    if (img==0){
      #pragma unroll
      for (int j=0;j<4;j++){ q0o0[j]=__fdividef(n0[j],d0[j]); q0o1[j]=__fdividef(n1[j],d1[j]); }
    } else {
      #pragma unroll
      for (int j=0;j<4;j++){
        float a = q0o0[j]-__fdividef(n0[j],d0[j]); vacc += a*a;
        float b2= q0o1[j]-__fdividef(n1[j],d1[j]); vacc += b2*b2;
      }
    }
  }
  #pragma unroll
  for (int off=32; off>0; off>>=1) vacc += __shfl_down(vacc, off);
  if ((tid&63)==0) S->red[tid>>6] = vacc;
  __syncthreads();
  if (tid==0)
    atomicAdd(&accum[lev*16+b], S->red[0]+S->red[1]+S->red[2]+S->red[3]);
}

// ================= tail (levels 3..6) helpers =================
static __device__ __forceinline__ void down_lds(const float* Ain, int ldi, int Sin,
                                                float* Aout, int ldo, int Sout,
                                                int tid, int NT){
  int tot = 2*Sout*Sout;
  for (int f=tid; f<tot; f+=NT){
    int img = f/(Sout*Sout), rem = f%(Sout*Sout), y=rem/Sout, x=rem%Sout;
    const float* A = Ain + img*Sin*ldi;
    float s=0.f;
    #pragma unroll
    for (int i=0;i<5;i++){
      int yy=iclamp(2*y+i-2,0,Sin-1);
      float rs=0.f;
      #pragma unroll
      for (int j=0;j<5;j++){
        int xx=iclamp(2*x+j-2,0,Sin-1);
        rs += c_f1d[j]*A[yy*ldi+xx];
      }
      s += c_f1d[i]*rs;
    }
    Aout[img*Sout*ldo + y*ldo + x] = s;
  }
}

static __device__ __forceinline__ void lap_lds(float* Ak, int ldk, int S,
                                               const float* Ag, int ldg,
                                               int tid, int NT){
  int Sg = S>>1;
  int tot = 2*S*S;
  for (int f=tid; f<tot; f+=NT){
    int img=f/(S*S), rem=f%(S*S), y=rem/S, x=rem%S;
    const float* G = Ag + img*Sg*ldg;
    int y2=y>>1, x2=x>>1;
    int ry0,ry1,ry2; float wy0,wy1,wy2;
    if (!(y&1)){ ry0=iclamp(y2-1,0,Sg-1); ry1=y2; ry2=iclamp(y2+1,0,Sg-1); wy0=0.2f; wy1=1.6f; wy2=0.2f; }
    else { ry0=y2; ry1=iclamp(y2+1,0,Sg-1); ry2=y2; wy0=1.f; wy1=1.f; wy2=0.f; }
    int cx0,cx1,cx2; float wx0,wx1,wx2;
    if (!(x&1)){ cx0=iclamp(x2-1,0,Sg-1); cx1=x2; cx2=iclamp(x2+1,0,Sg-1); wx0=0.05f; wx1=0.4f; wx2=0.05f; }
    else { cx0=x2; cx1=iclamp(x2+1,0,Sg-1); cx2=x2; wx0=0.25f; wx1=0.25f; wx2=0.f; }
    float u0 = wx0*G[ry0*ldg+cx0]+wx1*G[ry0*ldg+cx1]+wx2*G[ry0*ldg+cx2];
    float u1 = wx0*G[ry1*ldg+cx0]+wx1*G[ry1*ldg+cx1]+wx2*G[ry1*ldg+cx2];
    float u2 = wx0*G[ry2*ldg+cx0]+wx1*G[ry2*ldg+cx1]+wx2*G[ry2*ldg+cx2];
    Ak[img*S*ldk + y*ldk + x] -= wy0*u0+wy1*u1+wy2*u2;
  }
}

static __device__ __forceinline__ float diff_lds(const float* A, int ld, int S,
                                                 int tid, int NT){
  float v=0.f;
  const float* Ah = A;
  const float* Al = A + S*ld;
  for (int f=tid; f<S*S; f+=NT){
    int y=f/S, x=f%S;
    float dh=SIG0, dl=SIG0;
    #pragma unroll
    for (int i=0;i<5;i++){
      int yy=iclamp(y+i-2,0,S-1);
      #pragma unroll
      for (int j=0;j<5;j++){
        int xx=iclamp(x+j-2,0,S-1);
        float w=c_filt0[i*5+j];
        dh += w*fabsf(Ah[yy*ld+xx]);
        dl += w*fabsf(Al[yy*ld+xx]);
      }
    }
    float d = __fdividef(Ah[y*ld+x],dh) - __fdividef(Al[y*ld+x],dl);
    v += d*d;
  }
  return v;
}

__device__ void tail_body(const float* __restrict__ g3, float* __restrict__ accum,
                          int b, char* smem){
  TS* T = (TS*)smem;
  int tid = threadIdx.x;
  const float* s0  = g3 + (size_t)b*4896 + 148;        // 2*72+4
  const float* s1p = g3 + (size_t)(b+16)*4896 + 148;
  for (int f=tid; f<2*4096; f+=256){
    int img=f>>12, rem=f&4095, r=rem>>6, c=rem&63;
    T->A3[img][r][c] = (img? s1p : s0)[(size_t)r*72+c];
  }
  __syncthreads();
  down_lds(&T->A3[0][0][0],66,64,&T->A4[0][0][0],34,32,tid,256);
  __syncthreads();
  down_lds(&T->A4[0][0][0],34,32,&T->A5[0][0][0],18,16,tid,256);
  __syncthreads();
  down_lds(&T->A5[0][0][0],18,16,&T->A6[0][0][0],10,8,tid,256);
  __syncthreads();
  lap_lds(&T->A3[0][0][0],66,64,&T->A4[0][0][0],34,tid,256);
  __syncthreads();
  float v3 = diff_lds(&T->A3[0][0][0],66,64,tid,256);
  lap_lds(&T->A4[0][0][0],34,32,&T->A5[0][0][0],18,tid,256);
  __syncthreads();
  float v4 = diff_lds(&T->A4[0][0][0],34,32,tid,256);
  lap_lds(&T->A5[0][0][0],18,16,&T->A6[0][0][0],10,tid,256);
  __syncthreads();
  float v5 = diff_lds(&T->A5[0][0][0],18,16,tid,256);
  float v6 = 0.f;
  for (int f=tid; f<64; f+=256){
    float ch = T->A6[0][f>>3][f&7];
    float cl = T->A6[1][f>>3][f&7];
    float d = __fdividef(ch, fabsf(ch)+SIG1) - __fdividef(cl, fabsf(cl)+SIG1);
    v6 += d*d;
  }
  float vs[4] = {v3, v4, v5, v6};
  #pragma unroll
  for (int k=0;k<4;k++){
    float v = vs[k];
    #pragma unroll
    for (int off=32; off>0; off>>=1) v += __shfl_down(v, off);
    if ((tid&63)==0) T->red[tid>>6] = v;
    __syncthreads();
    if (tid==0){
      accum[(3+k)*16 + b] = T->red[0]+T->red[1]+T->red[2]+T->red[3];
    }
    __syncthreads();
  }
}

// ================= co-launched dispatch kernels =================
__global__ __launch_bounds__(256)
void k_d2(const float* __restrict__ h, const float* __restrict__ l,
          const float* __restrict__ g1, float* __restrict__ g2,
          float* __restrict__ accum){
  extern __shared__ char smem[];
  if (blockIdx.z < 16){
    FS* S = (FS*)smem;
    int b = blockIdx.z, x0 = blockIdx.x*64, y0 = blockIdx.y*32;
    fused_stage_in(S, h+(size_t)b*262144, l+(size_t)b*262144, x0, y0);
    fused_stage_s1(S, g1+(size_t)b*68640, g1+(size_t)(b+16)*68640, 264, x0, y0);
    fused_tail(S, 512, x0, y0, accum, 0, b);
  } else {
    int id = (blockIdx.z-16)*128 + blockIdx.y*8 + blockIdx.x;
    int db = id>>4, dby = (id>>1)&7, dbx = id&1;
    down_body(g1+(size_t)db*68640, g2+(size_t)db*17952, 264, 136, 128, dbx*64, dby*16, smem);
  }
}

__global__ __launch_bounds__(256)
void k_d4(const float* __restrict__ g1, float* __restrict__ g2,
          float* __restrict__ g3, float* __restrict__ accum){
  extern __shared__ char smem[];
  if (blockIdx.z < 16){
    FS* S = (FS*)smem;
    int b = blockIdx.z, x0 = blockIdx.x*64, y0 = blockIdx.y*32;
    fused_stage_g(S, g1+(size_t)b*68640, g1+(size_t)(b+16)*68640, 264, x0, y0);
    fused_stage_s1(S, g2+(size_t)b*17952, g2+(size_t)(b+16)*17952, 136, x0, y0);
    fused_tail(S, 256, x0, y0, accum, 1, b);
  } else {
    int id = (blockIdx.z-16)*32 + blockIdx.y*4 + blockIdx.x;
    int db = id>>2, dby = id&3;
    down_body(g2+(size_t)db*17952, g3+(size_t)db*4896, 136, 72, 64, 0, dby*16, smem);
  }
}

__global__ __launch_bounds__(256)
void k_d5(const float* __restrict__ g2, const float* __restrict__ g3,
          float* __restrict__ accum){
  extern __shared__ char smem[];
  if (blockIdx.z < 16){
    FS* S = (FS*)smem;
    int b = blockIdx.z, x0 = blockIdx.x*64, y0 = blockIdx.y*32;
    fused_stage_g(S, g2+(size_t)b*17952, g2+(size_t)(b+16)*17952, 136, x0, y0);
    fused_stage_s1(S, g3+(size_t)b*4896, g3+(size_t)(b+16)*4896, 72, x0, y0);
    fused_tail(S, 128, x0, y0, accum, 2, b);
  } else {
    int id = (blockIdx.z-16)*8 + blockIdx.y*2 + blockIdx.x;
    tail_body(g3, accum, id, smem);
  }
}

// ================= finalize =================
__global__ __launch_bounds__(64)
void k_d6(const float* __restrict__ accum, float* __restrict__ out){
  __shared__ float s[16];
  int b = threadIdx.x;
  if (b < 16){
    float m = 0.f;
    #pragma unroll
    for (int k=0;k<7;k++){
      int hw = (512>>k)*(512>>k);
      float mean = accum[k*16+b] / (float)hw;
      m += powf(mean, 0.3f);
    }
    m *= (1.0f/7.0f);
    s[b] = powf(m, 1.6666666666666667f);
  }
  __syncthreads();
  if (b == 0){
    float t = 0.f;
    #pragma unroll
    for (int i=0;i<16;i++) t += s[i];
    out[0] = t * (1.0f/16.0f);
  }
}

extern "C" void kernel_launch(void* const* d_in, const int* in_sizes, int n_in,
                              void* d_out, int out_size, void* d_ws, size_t ws_size,
                              hipStream_t stream){
  const float* h = (const float*)d_in[0];
  const float* l = (const float*)d_in[1];
  float* out = (float*)d_out;
  float* ws = (float*)d_ws;

  float* g1 = ws;                         // 32 * 260*264 = 2,196,480 floats
  float* g2 = g1 + 2196480;               // 32 * 132*136 = 574,464
  float* g3 = g2 + 574464;                // 32 * 68*72   = 156,672
  float* accum = g3 + 156672;             // 112

  hipMemsetAsync(accum, 0, 112*sizeof(float), stream);

  k_d1<<<dim3(4,16,32), 256, 0, stream>>>(h, l, g1);
  k_d2<<<dim3(8,16,20), 256, sizeof(FS), stream>>>(h, l, g1, g2, accum);
  k_d4<<<dim3(4,8,20),  256, sizeof(FS), stream>>>(g1, g2, g3, accum);
  k_d5<<<dim3(2,4,18),  256, sizeof(TS), stream>>>(g2, g3, accum);
  k_d6<<<1, 64, 0, stream>>>(accum, out);
}

// Round 6
// 172.788 us; speedup vs baseline: 2.5048x; 1.0085x over previous
//
#include <hip/hip_runtime.h>

#define SIG0 0.17f
#define SIG1 4.86f

__device__ __constant__ float c_filt0[25] = {
  0.04f,0.04f,0.05f,0.04f,0.04f,
  0.04f,0.03f,0.04f,0.03f,0.04f,
  0.05f,0.04f,0.05f,0.04f,0.05f,
  0.04f,0.03f,0.04f,0.03f,0.04f,
  0.04f,0.04f,0.05f,0.04f,0.04f};
__device__ __constant__ float c_f1d[5] = {0.05f,0.25f,0.4f,0.25f,0.05f};

static __device__ __forceinline__ int iclamp(int v, int lo, int hi){
  return v < lo ? lo : (v > hi ? hi : v);
}

// Padded level buffers: level size S stored as (S+4) rows x (S+8) cols,
// logical (y,x) at [(y+2)*(S+8) + (x+4)], apron = replicate of border.
// g1: S=256 PS=264 (img stride 68640); g2: S=128 PS=136 (17952); g3: S=64 PS=72 (4896)

struct FS {                      // fused kernel
  float sg[2][36][76];           // lap tile: rows y0-2..y0+33, cols x0-4..x0+67
  float s1[2][20][44];           // g_{k+1} tile
  float qbuf[128*20];            // img1 q-exchange (stride 20 to dodge bank alias)
  float red[4];
};
struct DS {                      // down kernel
  float st[36][136];
  float hs[36][64];
};
struct TS {                      // tail kernel
  float A3[2][64][66];
  float A4[2][32][34];
  float A5[2][16][18];
  float A6[2][8][10];
  float red[4];
};

// ================= down body: padded in -> padded out (out tile 64x16) =================
__device__ __forceinline__ void down_body(const float* __restrict__ in0, float* __restrict__ out0,
                                          int PSI, int PSO, int Sout, int xo0, int yo0, char* smem){
  DS* S = (DS*)smem;
  int tid = threadIdx.x;
  for (int f=tid; f<36*34; f+=256){
    int r=f/34, c4=f%34;
    *(float4*)&S->st[r][4*c4] = *(const float4*)&in0[(size_t)(2*yo0+r)*PSI + 2*xo0 + 4*c4];
  }
  __syncthreads();
  for (int f=tid; f<36*64; f+=256){
    int r=f>>6, xo=f&63;
    const float* rp = &S->st[r][2*xo+2];
    S->hs[r][xo] = 0.05f*rp[0]+0.25f*rp[1]+0.4f*rp[2]+0.25f*rp[3]+0.05f*rp[4];
  }
  __syncthreads();
  for (int f=tid; f<16*64; f+=256){
    int yo=f>>6, xo=f&63;
    int Y=yo0+yo, X=xo0+xo;
    float v = 0.05f*S->hs[2*yo][xo]+0.25f*S->hs[2*yo+1][xo]+0.4f*S->hs[2*yo+2][xo]
            +0.25f*S->hs[2*yo+3][xo]+0.05f*S->hs[2*yo+4][xo];
    int rlo=(Y==0)?0:(Y+2), rhi=(Y==Sout-1)?(Sout+3):(Y+2);
    int clo=(X==0)?0:(X+4), chi=(X==Sout-1)?(Sout+7):(X+4);
    for (int rr=rlo; rr<=rhi; rr++)
      for (int cc=clo; cc<=chi; cc++)
        out0[(size_t)rr*PSO+cc] = v;
  }
}

// ================= k_d1: gamma + down0 (raw input -> padded g1) =================
__global__ __launch_bounds__(256)
void k_d1(const float* __restrict__ hin, const float* __restrict__ lin,
          float* __restrict__ g1){
  __shared__ DS S;
  int xo0 = blockIdx.x*64, yo0 = blockIdx.y*16, z = blockIdx.z;
  const float* in = (z<16)? hin + (size_t)z*262144 : lin + (size_t)(z-16)*262144;
  float* out0 = g1 + (size_t)z*68640;
  int tid = threadIdx.x;
  const float e = 0.3846153846153846f;
  for (int f=tid; f<36*34; f+=256){
    int r=f/34, c4=f%34;
    int yy = iclamp(2*yo0-2+r, 0, 511);
    int xb = 2*xo0-4+4*c4;
    const float* rp = in + (size_t)yy*512;
    float4 v;
    if (xb>=0 && xb<=508) v = *(const float4*)&rp[xb];
    else { v.x=rp[iclamp(xb,0,511)]; v.y=rp[iclamp(xb+1,0,511)];
           v.z=rp[iclamp(xb+2,0,511)]; v.w=rp[iclamp(xb+3,0,511)]; }
    v.x=__powf(v.x,e); v.y=__powf(v.y,e); v.z=__powf(v.z,e); v.w=__powf(v.w,e);
    *(float4*)&S.st[r][4*c4] = v;
  }
  __syncthreads();
  for (int f=tid; f<36*64; f+=256){
    int r=f>>6, xo=f&63;
    const float* rp = &S.st[r][2*xo+2];
    S.hs[r][xo] = 0.05f*rp[0]+0.25f*rp[1]+0.4f*rp[2]+0.25f*rp[3]+0.05f*rp[4];
  }
  __syncthreads();
  for (int f=tid; f<16*64; f+=256){
    int yo=f>>6, xo=f&63;
    int Y=yo0+yo, X=xo0+xo;
    float v = 0.05f*S.hs[2*yo][xo]+0.25f*S.hs[2*yo+1][xo]+0.4f*S.hs[2*yo+2][xo]
            +0.25f*S.hs[2*yo+3][xo]+0.05f*S.hs[2*yo+4][xo];
    int rlo=(Y==0)?0:(Y+2), rhi=(Y==255)?259:(Y+2);
    int clo=(X==0)?0:(X+4), chi=(X==255)?263:(X+4);
    for (int rr=rlo; rr<=rhi; rr++)
      for (int cc=clo; cc<=chi; cc++)
        out0[(size_t)rr*264+cc] = v;
  }
}

// ================= fused staging =================
__device__ __forceinline__ void fused_stage_s1(FS* S, const float* __restrict__ g10,
                                               const float* __restrict__ g11,
                                               int PS1, int x0, int y0){
  int tid = threadIdx.x;
  for (int f=tid; f<400; f+=256){
    int img = f>=200; int fi = img ? f-200 : f;
    int ro = fi/10, co = fi - 10*ro;
    const float* src = img? g11 : g10;
    *(float4*)&S->s1[img][ro][4*co] = *(const float4*)&src[(size_t)(y0/2+ro)*PS1 + x0/2 + 4*co];
  }
}

__device__ __forceinline__ void fused_stage_g(FS* S, const float* __restrict__ gk0,
                                              const float* __restrict__ gk1,
                                              int PS0, int x0, int y0){
  int tid = threadIdx.x;
  for (int f=tid; f<1296; f+=256){
    int img = f>=648; int fi = img ? f-648 : f;
    int r = fi/18, q = fi - 18*r;
    const float* src = img? gk1 : gk0;
    *(float4*)&S->sg[img][r][4*q] = *(const float4*)&src[(size_t)(y0+r)*PS0 + x0 + 4*q];
  }
}

__device__ __forceinline__ void fused_stage_in(FS* S, const float* __restrict__ h0,
                                               const float* __restrict__ l0,
                                               int x0, int y0){
  int tid = threadIdx.x;
  const float e = 0.3846153846153846f;
  for (int f=tid; f<1296; f+=256){
    int img = f>=648; int fi = img ? f-648 : f;
    int r = fi/18, q = fi - 18*r;
    const float* src = img? l0 : h0;
    int yy = iclamp(y0-2+r, 0, 511);
    int xb = x0-4+4*q;
    const float* rp = src + (size_t)yy*512;
    float4 v;
    if (xb>=0 && xb<=508) v = *(const float4*)&rp[xb];
    else { v.x=rp[iclamp(xb,0,511)]; v.y=rp[iclamp(xb+1,0,511)];
           v.z=rp[iclamp(xb+2,0,511)]; v.w=rp[iclamp(xb+3,0,511)]; }
    v.x=__powf(v.x,e); v.y=__powf(v.y,e); v.z=__powf(v.z,e); v.w=__powf(v.w,e);
    *(float4*)&S->sg[img][r][4*q] = v;
  }
}

// up_row: horizontal upsample taps for one s1 row, chunk base col 2q
__device__ __forceinline__ float4 up_row(const float* __restrict__ p){
  float2 A = *(const float2*)p;
  float2 B = *(const float2*)(p+2);
  float2 C = *(const float2*)(p+4);
  float4 t;
  t.x = 0.05f*A.y + 0.4f*B.x + 0.05f*B.y;
  t.y = 0.25f*(B.x+B.y);
  t.z = 0.05f*B.x + 0.4f*B.y + 0.05f*C.x;
  t.w = 0.25f*(B.y+C.x);
  return t;
}

// ================= fused tail: lap + replicate-fix + box-trick den + diff + reduce =================
__device__ __forceinline__ void fused_tail(FS* S, int Simg, int x0, int y0,
                                           float* __restrict__ accum, int lev, int b){
  int tid = threadIdx.x;
  __syncthreads();   // staging complete

  // p2: lap in place
  for (int f=tid; f<1296; f+=256){
    int img = f>=648; int fi = img ? f-648 : f;
    int r = fi/18, q = fi - 18*r;
    int ry = ((r-2)>>1)+2;
    int cq = 2*q;
    float4 u;
    if ((r&1)==0){
      float4 a = up_row(&S->s1[img][ry-1][cq]);
      float4 m = up_row(&S->s1[img][ry  ][cq]);
      float4 c2= up_row(&S->s1[img][ry+1][cq]);
      u.x = 0.2f*a.x+1.6f*m.x+0.2f*c2.x;
      u.y = 0.2f*a.y+1.6f*m.y+0.2f*c2.y;
      u.z = 0.2f*a.z+1.6f*m.z+0.2f*c2.z;
      u.w = 0.2f*a.w+1.6f*m.w+0.2f*c2.w;
    } else {
      float4 a = up_row(&S->s1[img][ry  ][cq]);
      float4 m = up_row(&S->s1[img][ry+1][cq]);
      u.x=a.x+m.x; u.y=a.y+m.y; u.z=a.z+m.z; u.w=a.w+m.w;
    }
    float4 val = *(float4*)&S->sg[img][r][4*q];
    val.x-=u.x; val.y-=u.y; val.z-=u.z; val.w-=u.w;
    *(float4*)&S->sg[img][r][4*q] = val;
  }
  __syncthreads();

  // replicate fix-up on lap tile borders
  bool top=(y0==0), bot=(y0+32==Simg), lft=(x0==0), rgt=(x0+64==Simg);
  if (top||bot||lft||rgt){
    for (int f=tid; f<2*18; f+=256){
      int img=f/18, q=f%18;
      if (top){ float4 v=*(float4*)&S->sg[img][2][4*q];
                *(float4*)&S->sg[img][0][4*q]=v; *(float4*)&S->sg[img][1][4*q]=v; }
      if (bot){ float4 v=*(float4*)&S->sg[img][33][4*q];
                *(float4*)&S->sg[img][34][4*q]=v; *(float4*)&S->sg[img][35][4*q]=v; }
    }
    __syncthreads();
    for (int f=tid; f<2*36; f+=256){
      int img=f/36, r=f%36;
      if (lft){ float v=S->sg[img][r][4];  float4 vv={v,v,v,v}; *(float4*)&S->sg[img][r][0]=vv; }
      if (rgt){ float v=S->sg[img][r][67]; float4 vv={v,v,v,v}; *(float4*)&S->sg[img][r][68]=vv; }
    }
    __syncthreads();
  }

  // p3: box-trick den conv. Thread owns a 4x4 output quad of ONE image.
  // den = SIG0 + 0.04*T + 0.01*S05 - 0.01*S03
  // T = 5x5 box sum of |lap|; S05 = even cross (5 taps); S03 = odd diagonal (4 taps)
  int t = tid & 127;
  int img = tid >> 7;
  int qx = t & 15, qy = t >> 4;       // qy 0..7
  int r0 = 4*qy;                      // sg row base (covers rows r0..r0+7)
  int c0 = 4*qx + 2;                  // sg col base (window cols c0..c0+7)

  float a[8][8];
  #pragma unroll
  for (int r=0;r<8;r++){
    const float* rp = &S->sg[img][r0+r][c0];
    *(float2*)&a[r][0] = *(const float2*)&rp[0];
    *(float4*)&a[r][2] = *(const float4*)&rp[2];
    *(float2*)&a[r][6] = *(const float2*)&rp[6];
  }

  float h[8][4];
  #pragma unroll
  for (int r=0;r<8;r++){
    float s = ((fabsf(a[r][0])+fabsf(a[r][1])) + (fabsf(a[r][2])+fabsf(a[r][3]))) + fabsf(a[r][4]);
    h[r][0] = s;
    h[r][1] = h[r][0] - fabsf(a[r][0]) + fabsf(a[r][5]);
    h[r][2] = h[r][1] - fabsf(a[r][1]) + fabsf(a[r][6]);
    h[r][3] = h[r][2] - fabsf(a[r][2]) + fabsf(a[r][7]);
  }

  float q[4][4];
  #pragma unroll
  for (int c=0;c<4;c++){
    float T = (h[0][c]+h[1][c]) + (h[2][c]+h[3][c]) + h[4][c];
    #pragma unroll
    for (int k=0;k<4;k++){
      if (k) T += h[k+4][c] - h[k-1][c];
      float s05 = (fabsf(a[k][c+2]) + fabsf(a[k+2][c])) + (fabsf(a[k+2][c+2])
                + fabsf(a[k+2][c+4])) + fabsf(a[k+4][c+2]);
      float s03 = (fabsf(a[k+1][c+1]) + fabsf(a[k+1][c+3]))
                + (fabsf(a[k+3][c+1]) + fabsf(a[k+3][c+3]));
      float den = SIG0 + 0.04f*T + 0.01f*s05 - 0.01f*s03;
      q[k][c] = __fdividef(a[k+2][c+2], den);
    }
  }

  // exchange img1 q's through LDS, diff on img0 threads
  if (img==1){
    #pragma unroll
    for (int k=0;k<4;k++)
      *(float4*)&S->qbuf[t*20 + 4*k] = make_float4(q[k][0],q[k][1],q[k][2],q[k][3]);
  }
  __syncthreads();
  float vacc = 0.f;
  if (img==0){
    #pragma unroll
    for (int k=0;k<4;k++){
      float4 o = *(const float4*)&S->qbuf[t*20 + 4*k];
      float d0=q[k][0]-o.x, d1=q[k][1]-o.y, d2=q[k][2]-o.z, d3=q[k][3]-o.w;
      vacc += (d0*d0+d1*d1)+(d2*d2+d3*d3);
    }
  }
  #pragma unroll
  for (int off=32; off>0; off>>=1) vacc += __shfl_down(vacc, off);
  if ((tid&63)==0) S->red[tid>>6] = vacc;
  __syncthreads();
  if (tid==0)
    atomicAdd(&accum[lev*16+b], S->red[0]+S->red[1]+S->red[2]+S->red[3]);
}

// ================= tail (levels 3..6) helpers =================
static __device__ __forceinline__ void down_lds(const float* Ain, int ldi, int Sin,
                                                float* Aout, int ldo, int Sout,
                                                int tid, int NT){
  int tot = 2*Sout*Sout;
  for (int f=tid; f<tot; f+=NT){
    int img = f/(Sout*Sout), rem = f%(Sout*Sout), y=rem/Sout, x=rem%Sout;
    const float* A = Ain + img*Sin*ldi;
    float s=0.f;
    #pragma unroll
    for (int i=0;i<5;i++){
      int yy=iclamp(2*y+i-2,0,Sin-1);
      float rs=0.f;
      #pragma unroll
      for (int j=0;j<5;j++){
        int xx=iclamp(2*x+j-2,0,Sin-1);
        rs += c_f1d[j]*A[yy*ldi+xx];
      }
      s += c_f1d[i]*rs;
    }
    Aout[img*Sout*ldo + y*ldo + x] = s;
  }
}

static __device__ __forceinline__ void lap_lds(float* Ak, int ldk, int S,
                                               const float* Ag, int ldg,
                                               int tid, int NT){
  int Sg = S>>1;
  int tot = 2*S*S;
  for (int f=tid; f<tot; f+=NT){
    int img=f/(S*S), rem=f%(S*S), y=rem/S, x=rem%S;
    const float* G = Ag + img*Sg*ldg;
    int y2=y>>1, x2=x>>1;
    int ry0,ry1,ry2; float wy0,wy1,wy2;
    if (!(y&1)){ ry0=iclamp(y2-1,0,Sg-1); ry1=y2; ry2=iclamp(y2+1,0,Sg-1); wy0=0.2f; wy1=1.6f; wy2=0.2f; }
    else { ry0=y2; ry1=iclamp(y2+1,0,Sg-1); ry2=y2; wy0=1.f; wy1=1.f; wy2=0.f; }
    int cx0,cx1,cx2; float wx0,wx1,wx2;
    if (!(x&1)){ cx0=iclamp(x2-1,0,Sg-1); cx1=x2; cx2=iclamp(x2+1,0,Sg-1); wx0=0.05f; wx1=0.4f; wx2=0.05f; }
    else { cx0=x2; cx1=iclamp(x2+1,0,Sg-1); cx2=x2; wx0=0.25f; wx1=0.25f; wx2=0.f; }
    float u0 = wx0*G[ry0*ldg+cx0]+wx1*G[ry0*ldg+cx1]+wx2*G[ry0*ldg+cx2];
    float u1 = wx0*G[ry1*ldg+cx0]+wx1*G[ry1*ldg+cx1]+wx2*G[ry1*ldg+cx2];
    float u2 = wx0*G[ry2*ldg+cx0]+wx1*G[ry2*ldg+cx1]+wx2*G[ry2*ldg+cx2];
    Ak[img*S*ldk + y*ldk + x] -= wy0*u0+wy1*u1+wy2*u2;
  }
}

static __device__ __forceinline__ float diff_lds(const float* A, int ld, int S,
                                                 int tid, int NT){
  float v=0.f;
  const float* Ah = A;
  const float* Al = A + S*ld;
  for (int f=tid; f<S*S; f+=NT){
    int y=f/S, x=f%S;
    float dh=SIG0, dl=SIG0;
    #pragma unroll
    for (int i=0;i<5;i++){
      int yy=iclamp(y+i-2,0,S-1);
      #pragma unroll
      for (int j=0;j<5;j++){
        int xx=iclamp(x+j-2,0,S-1);
        float w=c_filt0[i*5+j];
        dh += w*fabsf(Ah[yy*ld+xx]);
        dl += w*fabsf(Al[yy*ld+xx]);
      }
    }
    float d = __fdividef(Ah[y*ld+x],dh) - __fdividef(Al[y*ld+x],dl);
    v += d*d;
  }
  return v;
}

__device__ void tail_body(const float* __restrict__ g3, float* __restrict__ accum,
                          int b, char* smem){
  TS* T = (TS*)smem;
  int tid = threadIdx.x;
  const float* s0  = g3 + (size_t)b*4896 + 148;
  const float* s1p = g3 + (size_t)(b+16)*4896 + 148;
  for (int f=tid; f<2*4096; f+=256){
    int img=f>>12, rem=f&4095, r=rem>>6, c=rem&63;
    T->A3[img][r][c] = (img? s1p : s0)[(size_t)r*72+c];
  }
  __syncthreads();
  down_lds(&T->A3[0][0][0],66,64,&T->A4[0][0][0],34,32,tid,256);
  __syncthreads();
  down_lds(&T->A4[0][0][0],34,32,&T->A5[0][0][0],18,16,tid,256);
  __syncthreads();
  down_lds(&T->A5[0][0][0],18,16,&T->A6[0][0][0],10,8,tid,256);
  __syncthreads();
  lap_lds(&T->A3[0][0][0],66,64,&T->A4[0][0][0],34,tid,256);
  __syncthreads();
  float v3 = diff_lds(&T->A3[0][0][0],66,64,tid,256);
  lap_lds(&T->A4[0][0][0],34,32,&T->A5[0][0][0],18,tid,256);
  __syncthreads();
  float v4 = diff_lds(&T->A4[0][0][0],34,32,tid,256);
  lap_lds(&T->A5[0][0][0],18,16,&T->A6[0][0][0],10,tid,256);
  __syncthreads();
  float v5 = diff_lds(&T->A5[0][0][0],18,16,tid,256);
  float v6 = 0.f;
  for (int f=tid; f<64; f+=256){
    float ch = T->A6[0][f>>3][f&7];
    float cl = T->A6[1][f>>3][f&7];
    float d = __fdividef(ch, fabsf(ch)+SIG1) - __fdividef(cl, fabsf(cl)+SIG1);
    v6 += d*d;
  }
  float vs[4] = {v3, v4, v5, v6};
  #pragma unroll
  for (int k=0;k<4;k++){
    float v = vs[k];
    #pragma unroll
    for (int off=32; off>0; off>>=1) v += __shfl_down(v, off);
    if ((tid&63)==0) T->red[tid>>6] = v;
    __syncthreads();
    if (tid==0){
      accum[(3+k)*16 + b] = T->red[0]+T->red[1]+T->red[2]+T->red[3];
    }
    __syncthreads();
  }
}

// ================= co-launched dispatch kernels =================
__global__ __launch_bounds__(256)
void k_d2(const float* __restrict__ h, const float* __restrict__ l,
          const float* __restrict__ g1, float* __restrict__ g2,
          float* __restrict__ accum){
  extern __shared__ char smem[];
  if (blockIdx.z < 16){
    FS* S = (FS*)smem;
    int b = blockIdx.z, x0 = blockIdx.x*64, y0 = blockIdx.y*32;
    fused_stage_in(S, h+(size_t)b*262144, l+(size_t)b*262144, x0, y0);
    fused_stage_s1(S, g1+(size_t)b*68640, g1+(size_t)(b+16)*68640, 264, x0, y0);
    fused_tail(S, 512, x0, y0, accum, 0, b);
  } else {
    int id = (blockIdx.z-16)*128 + blockIdx.y*8 + blockIdx.x;
    int db = id>>4, dby = (id>>1)&7, dbx = id&1;
    down_body(g1+(size_t)db*68640, g2+(size_t)db*17952, 264, 136, 128, dbx*64, dby*16, smem);
  }
}

__global__ __launch_bounds__(256)
void k_d4(const float* __restrict__ g1, float* __restrict__ g2,
          float* __restrict__ g3, float* __restrict__ accum){
  extern __shared__ char smem[];
  if (blockIdx.z < 16){
    FS* S = (FS*)smem;
    int b = blockIdx.z, x0 = blockIdx.x*64, y0 = blockIdx.y*32;
    fused_stage_g(S, g1+(size_t)b*68640, g1+(size_t)(b+16)*68640, 264, x0, y0);
    fused_stage_s1(S, g2+(size_t)b*17952, g2+(size_t)(b+16)*17952, 136, x0, y0);
    fused_tail(S, 256, x0, y0, accum, 1, b);
  } else {
    int id = (blockIdx.z-16)*32 + blockIdx.y*4 + blockIdx.x;
    int db = id>>2, dby = id&3;
    down_body(g2+(size_t)db*17952, g3+(size_t)db*4896, 136, 72, 64, 0, dby*16, smem);
  }
}

__global__ __launch_bounds__(256)
void k_d5(const float* __restrict__ g2, const float* __restrict__ g3,
          float* __restrict__ accum){
  extern __shared__ char smem[];
  if (blockIdx.z < 16){
    FS* S = (FS*)smem;
    int b = blockIdx.z, x0 = blockIdx.x*64, y0 = blockIdx.y*32;
    fused_stage_g(S, g2+(size_t)b*17952, g2+(size_t)(b+16)*17952, 136, x0, y0);
    fused_stage_s1(S, g3+(size_t)b*4896, g3+(size_t)(b+16)*4896, 72, x0, y0);
    fused_tail(S, 128, x0, y0, accum, 2, b);
  } else {
    int id = (blockIdx.z-16)*8 + blockIdx.y*2 + blockIdx.x;
    tail_body(g3, accum, id, smem);
  }
}

// ================= finalize =================
__global__ __launch_bounds__(64)
void k_d6(const float* __restrict__ accum, float* __restrict__ out){
  __shared__ float s[16];
  int b = threadIdx.x;
  if (b < 16){
    float m = 0.f;
    #pragma unroll
    for (int k=0;k<7;k++){
      int hw = (512>>k)*(512>>k);
      float mean = accum[k*16+b] / (float)hw;
      m += powf(mean, 0.3f);
    }
    m *= (1.0f/7.0f);
    s[b] = powf(m, 1.6666666666666667f);
  }
  __syncthreads();
  if (b == 0){
    float t = 0.f;
    #pragma unroll
    for (int i=0;i<16;i++) t += s[i];
    out[0] = t * (1.0f/16.0f);
  }
}

extern "C" void kernel_launch(void* const* d_in, const int* in_sizes, int n_in,
                              void* d_out, int out_size, void* d_ws, size_t ws_size,
                              hipStream_t stream){
  const float* h = (const float*)d_in[0];
  const float* l = (const float*)d_in[1];
  float* out = (float*)d_out;
  float* ws = (float*)d_ws;

  float* g1 = ws;                         // 32 * 260*264
  float* g2 = g1 + 2196480;               // 32 * 132*136
  float* g3 = g2 + 574464;                // 32 * 68*72
  float* accum = g3 + 156672;             // 112

  hipMemsetAsync(accum, 0, 112*sizeof(float), stream);

  k_d1<<<dim3(4,16,32), 256, 0, stream>>>(h, l, g1);
  k_d2<<<dim3(8,16,20), 256, sizeof(FS), stream>>>(h, l, g1, g2, accum);
  k_d4<<<dim3(4,8,20),  256, sizeof(FS), stream>>>(g1, g2, g3, accum);
  k_d5<<<dim3(2,4,18),  256, sizeof(TS), stream>>>(g2, g3, accum);
  k_d6<<<1, 64, 0, stream>>>(accum, out);
}